// Round 1
// baseline (10615.955 us; speedup 1.0000x reference)
//
#include <hip/hip_runtime.h>
#include <math.h>

#define AGENTS __HIP_MEMORY_SCOPE_AGENT

constexpr int   CB   = 16;      // batches
constexpr int   CN   = 16384;   // inputs per batch
constexpr float LOG7 = 1.9459101090932196f;
constexpr float EPST = 1e-8f;

// ws layout (float offsets)
constexpr size_t OFF_PA  = 64;                       // [16][16][2]
constexpr size_t OFF_RED = 576;                      // [2][16][16][8]
constexpr size_t OFF_UPD = 4672;                     // [16][16][7][64]
constexpr size_t OFF_QSP = 119360;                   // [3][256][512]
constexpr size_t OFF_WQT = 512576;                   // [64][64]
constexpr size_t OFF_WIH = 516672;                   // [64][192]
constexpr size_t OFF_WHH = 528960;                   // [64][192]
constexpr size_t OFF_F1T = 541248;                   // [64][128]
constexpr size_t OFF_F2T = 549440;                   // [128][64]
constexpr size_t OFF_K   = 557632;                   // [16][16384][64]
constexpr size_t OFF_V   = OFF_K + (size_t)CB * CN * 64;

__device__ __forceinline__ float aload(const float* p) {
  return __hip_atomic_load(const_cast<float*>(p), __ATOMIC_RELAXED, AGENTS);
}
__device__ __forceinline__ void astore(float* p, float v) {
  __hip_atomic_store(p, v, __ATOMIC_RELAXED, AGENTS);
}
__device__ __forceinline__ float wsum64(float v) {
#pragma unroll
  for (int m = 1; m < 64; m <<= 1) v += __shfl_xor(v, m, 64);
  return v;
}
__device__ __forceinline__ float dot4(float4 a, float4 b) {
  return a.x * b.x + a.y * b.y + a.z * b.z + a.w * b.w;
}

__device__ __forceinline__ void batch_sync(unsigned* cnt, unsigned& tgt) {
  __threadfence();
  __syncthreads();
  tgt += 16;
  if (threadIdx.x == 0) {
    __hip_atomic_fetch_add(cnt, 1u, __ATOMIC_RELEASE, AGENTS);
    unsigned v;
    do {
      v = __hip_atomic_load(cnt, __ATOMIC_RELAXED, AGENTS);
      if (v < tgt) __builtin_amdgcn_s_sleep(1);
    } while (v < tgt);
    (void)__hip_atomic_load(cnt, __ATOMIC_ACQUIRE, AGENTS);
  }
  __syncthreads();
}

// reduce 7 per-thread values over all 16384 rows of the batch -> tot[0..6] (LDS)
__device__ __forceinline__ void reduce7_sync(float (&es)[7], float* __restrict__ wsp,
                                             float* s_redw, float* tot, int bb, int ib,
                                             unsigned* cnt, unsigned& tgt, int& rbuf) {
  const int tid = threadIdx.x, lane = tid & 63, wid = tid >> 6;
#pragma unroll
  for (int m = 1; m < 64; m <<= 1) {
#pragma unroll
    for (int s = 0; s < 7; ++s) es[s] += __shfl_xor(es[s], m, 64);
  }
  if (lane == 0) {
#pragma unroll
    for (int s = 0; s < 7; ++s) s_redw[wid * 8 + s] = es[s];
  }
  __syncthreads();
  float* rp = wsp + OFF_RED + (size_t)((rbuf * CB + bb) * 16) * 8;
  if (wid == 0) {
#pragma unroll
    for (int h = 0; h < 2; ++h) {
      int s = h * 4 + (lane >> 4);
      float v = 0.f;
      if (s < 7) v = s_redw[(lane & 15) * 8 + s];
      v += __shfl_xor(v, 1, 64); v += __shfl_xor(v, 2, 64);
      v += __shfl_xor(v, 4, 64); v += __shfl_xor(v, 8, 64);
      if ((lane & 15) == 0 && s < 7) astore(rp + ib * 8 + s, v);
    }
  }
  batch_sync(cnt, tgt);
  if (wid == 0) {
#pragma unroll
    for (int h = 0; h < 2; ++h) {
      int s = h * 4 + (lane >> 4);
      float v = 0.f;
      if (s < 7) v = aload(rp + (lane & 15) * 8 + s);
      v += __shfl_xor(v, 1, 64); v += __shfl_xor(v, 2, 64);
      v += __shfl_xor(v, 4, 64); v += __shfl_xor(v, 8, 64);
      if ((lane & 15) == 0 && s < 7) tot[s] = v;
    }
  }
  __syncthreads();
  rbuf ^= 1;
}

__global__ void prep_kernel(const float* __restrict__ Wq, const float* __restrict__ Wih,
                            const float* __restrict__ Whh, const float* __restrict__ f1,
                            const float* __restrict__ f2, float* __restrict__ w) {
  int idx = blockIdx.x * blockDim.x + threadIdx.x;
  int stride = gridDim.x * blockDim.x;
  if (idx < 16) reinterpret_cast<unsigned*>(w)[idx] = 0u;
  for (int i = idx; i < 64 * 64; i += stride) {
    int d = i / 64, j = i % 64;
    w[OFF_WQT + j * 64 + d] = Wq[d * 64 + j];
  }
  for (int i = idx; i < 192 * 64; i += stride) {
    int o = i / 64, j = i % 64;
    w[OFF_WIH + j * 192 + o] = Wih[o * 64 + j];
    w[OFF_WHH + j * 192 + o] = Whh[o * 64 + j];
  }
  for (int i = idx; i < 128 * 64; i += stride) {
    int o = i / 64, j = i % 64;
    w[OFF_F1T + j * 128 + o] = f1[o * 64 + j];
  }
  for (int i = idx; i < 64 * 128; i += stride) {
    int d = i / 128, j = i % 128;
    w[OFF_F2T + j * 64 + d] = f2[d * 128 + j];
  }
}

__launch_bounds__(1024, 4)
__global__ void slot_attn_kernel(
    const float* __restrict__ inputs, const float* __restrict__ sinit,
    const float* __restrict__ smu, const float* __restrict__ slsig,
    const float* __restrict__ Wk, const float* __restrict__ Wv,
    const float* __restrict__ gbih, const float* __restrict__ gbhh,
    const float* __restrict__ fc1b, const float* __restrict__ fc2b,
    const float* __restrict__ lin_g, const float* __restrict__ lin_b,
    const float* __restrict__ lsl_g, const float* __restrict__ lsl_b,
    const float* __restrict__ lff_g, const float* __restrict__ lff_b,
    const float* __restrict__ wi_W, const float* __restrict__ wi_b,
    const float* __restrict__ wsW, const float* __restrict__ wsB,
    float* __restrict__ out, float* __restrict__ w) {
  __shared__ float s_slots[448];
  __shared__ float s_snl[448];
  __shared__ float s_scr1[1344];
  __shared__ float s_scr2[1344];
  __shared__ float s_updl[448];
  __shared__ float s_T[8192];       // [1024][8]
  __shared__ float s_pupd[7168];    // [16][7][64]
  __shared__ float s_vh[48];        // v history [6][8]
  __shared__ float s_logb[8];
  __shared__ float s_gvl[8];
  __shared__ float s_tot[8];
  __shared__ float s_wl[8];
  __shared__ float s_redw[128];     // [16][8]
  __shared__ float s_misc[4];

  const int tid = threadIdx.x;
  const int lane = tid & 63, wid = tid >> 6;
  const int bb = blockIdx.x & 15;
  const int ib = blockIdx.x >> 4;
  const int nloc = ib * 1024 + tid;
  const size_t grow = (size_t)bb * CN + nloc;
  unsigned* cnt = reinterpret_cast<unsigned*>(w) + bb;
  unsigned tgt = 0;
  int rbuf = 0;
  float log_a;

  // ================= phase 0: LN + k/v/logit projections =================
  {
    const float* xin = inputs + grow * 64;
    float4 xa[16];
#pragma unroll
    for (int c = 0; c < 16; ++c) xa[c] = reinterpret_cast<const float4*>(xin)[c];
    float s1 = 0;
#pragma unroll
    for (int c = 0; c < 16; ++c) s1 += xa[c].x + xa[c].y + xa[c].z + xa[c].w;
    float mn = s1 * (1.f / 64.f);
    float s2 = 0;
#pragma unroll
    for (int c = 0; c < 16; ++c) {
      float dx = xa[c].x - mn, dy = xa[c].y - mn, dz = xa[c].z - mn, dw = xa[c].w - mn;
      s2 += dx * dx + dy * dy + dz * dz + dw * dw;
    }
    float rs = rsqrtf(s2 * (1.f / 64.f) + 1e-5f);
#pragma unroll
    for (int c = 0; c < 16; ++c) {
      float4 g4 = reinterpret_cast<const float4*>(lin_g)[c];
      float4 b4 = reinterpret_cast<const float4*>(lin_b)[c];
      xa[c].x = (xa[c].x - mn) * rs * g4.x + b4.x;
      xa[c].y = (xa[c].y - mn) * rs * g4.y + b4.y;
      xa[c].z = (xa[c].z - mn) * rs * g4.z + b4.z;
      xa[c].w = (xa[c].w - mn) * rs * g4.w + b4.w;
    }
    float lg = wi_b[0];
#pragma unroll
    for (int c = 0; c < 16; ++c) lg += dot4(xa[c], reinterpret_cast<const float4*>(wi_W)[c]);
    // k, v projections (W rows uniform -> scalar-cached loads)
#pragma unroll 1
    for (int half = 0; half < 2; ++half) {
      const float* W = half ? Wv : Wk;
      float* ob = w + (half ? OFF_V : OFF_K) + grow * 64;
#pragma unroll 1
      for (int oc = 0; oc < 8; ++oc) {
        float acc[8] = {0, 0, 0, 0, 0, 0, 0, 0};
#pragma unroll
        for (int c = 0; c < 16; ++c) {
          float4 xv = xa[c];
#pragma unroll
          for (int o8 = 0; o8 < 8; ++o8) {
            float4 w4 = reinterpret_cast<const float4*>(W + (size_t)(oc * 8 + o8) * 64)[c];
            acc[o8] += dot4(xv, w4);
          }
        }
        reinterpret_cast<float4*>(ob + oc * 8)[0] = make_float4(acc[0], acc[1], acc[2], acc[3]);
        reinterpret_cast<float4*>(ob + oc * 8)[1] = make_float4(acc[4], acc[5], acc[6], acc[7]);
      }
    }
    // batch softmax stats for 'a'
    float mx = lg;
#pragma unroll
    for (int m = 1; m < 64; m <<= 1) mx = fmaxf(mx, __shfl_xor(mx, m, 64));
    float se = wsum64(__expf(lg - mx));
    if (lane == 0) { s_redw[wid * 8 + 0] = mx; s_redw[wid * 8 + 1] = se; }
    __syncthreads();
    float* pa = w + OFF_PA + (size_t)bb * 32;
    if (wid == 0 && lane < 16) {
      float m0 = s_redw[lane * 8 + 0], e0 = s_redw[lane * 8 + 1];
#pragma unroll
      for (int mm = 1; mm < 16; mm <<= 1) {
        float m1 = __shfl_xor(m0, mm, 64), e1 = __shfl_xor(e0, mm, 64);
        float nm = fmaxf(m0, m1);
        e0 = e0 * __expf(m0 - nm) + e1 * __expf(m1 - nm);
        m0 = nm;
      }
      if (lane == 0) { astore(pa + ib * 2 + 0, m0); astore(pa + ib * 2 + 1, e0); }
    }
    batch_sync(cnt, tgt);
    if (wid == 0 && lane < 16) {
      float m0 = aload(pa + lane * 2 + 0), e0 = aload(pa + lane * 2 + 1);
#pragma unroll
      for (int mm = 1; mm < 16; mm <<= 1) {
        float m1 = __shfl_xor(m0, mm, 64), e1 = __shfl_xor(e0, mm, 64);
        float nm = fmaxf(m0, m1);
        e0 = e0 * __expf(m0 - nm) + e1 * __expf(m1 - nm);
        m0 = nm;
      }
      if (lane == 0) s_misc[0] = m0 + __logf(e0);
    }
    __syncthreads();
    log_a = lg - s_misc[0] + LOG7;
  }

  // slot phase common: LN(slots)->snl, q (+q2) spill, log_b
  auto slot_common = [&](int inst) {
    if (wid < 7) {
      float h = s_slots[wid * 64 + lane];
      float m = wsum64(h) * (1.f / 64.f);
      float d0 = h - m;
      float va = wsum64(d0 * d0) * (1.f / 64.f);
      float sn = d0 * rsqrtf(va + 1e-5f) * lsl_g[lane] + lsl_b[lane];
      s_snl[wid * 64 + lane] = sn;
      float pw = wsum64(sn * wsW[lane]);
      if (lane == 0) s_wl[wid] = pw + wsB[0];
    }
    __syncthreads();
    float* qsp = w + OFF_QSP + (size_t)(inst * 256 + blockIdx.x) * 512;
    if (tid < 448) {
      int s = tid >> 6, dd = tid & 63;
      float acc = 0;
#pragma unroll 4
      for (int j = 0; j < 64; ++j) acc += s_snl[s * 64 + j] * w[OFF_WQT + j * 64 + dd];
      qsp[s * 64 + dd] = acc;
      s_scr1[s * 64 + dd] = acc;
    }
    __syncthreads();
    if (wid < 7) {
      float qv = s_scr1[wid * 64 + lane];
      float q2 = wsum64(qv * qv);
      if (lane == 0) qsp[448 + wid] = q2;
    }
    if (tid == 0) {
      float mx = -1e30f;
#pragma unroll
      for (int s = 0; s < 7; ++s) mx = fmaxf(mx, s_wl[s]);
      float se = 0;
#pragma unroll
      for (int s = 0; s < 7; ++s) se += __expf(s_wl[s] - mx);
      float lse = mx + __logf(se);
#pragma unroll
      for (int s = 0; s < 7; ++s) s_logb[s] = s_wl[s] - lse + LOG7;
    }
    __syncthreads();
  };

  // init slots
  if (tid < 448) {
    int dd = tid & 63;
    s_slots[tid] = smu[dd] + __expf(slsig[dd]) * sinit[(size_t)bb * 448 + tid];
  }
  __syncthreads();
  slot_common(0);

  float p[7], u = 0.f;
  auto fwd5 = [&]() {
#pragma unroll 1
    for (int i = 1; i <= 5; ++i) {
      float t = 0;
#pragma unroll
      for (int s = 0; s < 7; ++s) t += __expf(p[s] + s_vh[(i - 1) * 8 + s]);
      u = log_a - __logf(t);
      float es[7];
#pragma unroll
      for (int s = 0; s < 7; ++s) es[s] = __expf(p[s] + u);
      reduce7_sync(es, w, s_redw, s_tot, bb, ib, cnt, tgt, rbuf);
      if (tid < 7) s_vh[i * 8 + tid] = s_logb[tid] - __logf(s_tot[tid]);
      __syncthreads();
    }
  };

#pragma unroll 1
  for (int it = 0; it < 3; ++it) {
    // ---- C = -cdist(k, q)
    {
      const float* kb = w + OFF_K + grow * 64;
      const float* qsp = w + OFF_QSP + (size_t)(it * 256 + blockIdx.x) * 512;
      float k2 = 0, kq[7] = {0, 0, 0, 0, 0, 0, 0};
#pragma unroll
      for (int c = 0; c < 16; ++c) {
        float4 kk = reinterpret_cast<const float4*>(kb)[c];
        k2 += dot4(kk, kk);
#pragma unroll
        for (int s = 0; s < 7; ++s)
          kq[s] += dot4(kk, reinterpret_cast<const float4*>(qsp + s * 64)[c]);
      }
#pragma unroll
      for (int s = 0; s < 7; ++s) {
        float sq = k2 + qsp[448 + s] - 2.f * kq[s];
        p[s] = -sqrtf(fmaxf(sq, 0.f) + 1e-12f);
      }
    }
    if (tid < 8) s_vh[tid] = 0.f;
    __syncthreads();

    // ---- MESH: 4 iterations of entropy-gradient descent on C
#pragma unroll 1
    for (int ms = 0; ms < 4; ++ms) {
      fwd5();
      float gp[7], guT = 0.f;
      {
        float es[7];
#pragma unroll
        for (int s = 0; s < 7; ++s) {
          float T = __expf(p[s] + u + s_vh[40 + s]);
          float gT = -(__logf(T + EPST) + T / (T + EPST));
          float g = gT * T;
          gp[s] = g; guT += g; es[s] = g;
        }
        reduce7_sync(es, w, s_redw, s_gvl, bb, ib, cnt, tgt, rbuf);  // gv_5
      }
#pragma unroll 1
      for (int i = 5; i >= 1; --i) {
        float t = 0;
#pragma unroll
        for (int s = 0; s < 7; ++s) t += __expf(p[s] + s_vh[(i - 1) * 8 + s]);
        float ui = log_a - __logf(t);
        float gu = (i == 5) ? guT : 0.f;
#pragma unroll
        for (int s = 0; s < 7; ++s) {
          float sn = __expf(p[s] + ui - s_logb[s] + s_vh[i * 8 + s]);
          float gz = -s_gvl[s] * sn;
          gp[s] += gz; gu += gz;
        }
        float gw[7];
#pragma unroll
        for (int s = 0; s < 7; ++s) {
          float sg = __expf(p[s] + s_vh[(i - 1) * 8 + s] - log_a + ui);
          gw[s] = -gu * sg;
          gp[s] += gw[s];
        }
        if (i > 1) reduce7_sync(gw, w, s_redw, s_gvl, bb, ib, cnt, tgt, rbuf);  // gv_{i-1}
      }
#pragma unroll
      for (int s = 0; s < 7; ++s) p[s] -= 5.0f * gp[s];
      if (tid < 8) s_vh[tid] = s_vh[40 + tid];  // warm-start v
      __syncthreads();
    }

    // ---- final sinkhorn (warm-started) -> attn row
    fwd5();
    float T7[7];
#pragma unroll
    for (int s = 0; s < 7; ++s) T7[s] = __expf(p[s] + u + s_vh[40 + s]);
    if (it == 2) {
      size_t ab = 7168 + (size_t)(bb * 7) * CN + nloc;
#pragma unroll
      for (int s = 0; s < 7; ++s) out[ab + (size_t)s * CN] = T7[s];
    }
#pragma unroll
    for (int s = 0; s < 7; ++s) s_T[tid * 8 + s] = T7[s];
    s_T[tid * 8 + 7] = 0.f;
    __syncthreads();

    // ---- updates = attn @ v  (per-wave column reduce, then batch combine)
    {
      const float* vb = w + OFF_V + (size_t)(bb * CN + ib * 1024 + wid * 64) * 64 + lane;
      float acc[7] = {0, 0, 0, 0, 0, 0, 0};
#pragma unroll 4
      for (int n = 0; n < 64; ++n) {
        float vv = vb[(size_t)n * 64];
        const float* tr = &s_T[(wid * 64 + n) * 8];
        acc[0] += tr[0] * vv; acc[1] += tr[1] * vv; acc[2] += tr[2] * vv;
        acc[3] += tr[3] * vv; acc[4] += tr[4] * vv; acc[5] += tr[5] * vv;
        acc[6] += tr[6] * vv;
      }
#pragma unroll
      for (int s = 0; s < 7; ++s) s_pupd[(wid * 7 + s) * 64 + lane] = acc[s];
    }
    __syncthreads();
    if (tid < 448) {
      int s = tid >> 6, dd = tid & 63;
      float t = 0;
#pragma unroll
      for (int w16 = 0; w16 < 16; ++w16) t += s_pupd[(w16 * 7 + s) * 64 + dd];
      astore(w + OFF_UPD + (size_t)((bb * 16 + ib) * 7 + s) * 64 + dd, t);
    }
    batch_sync(cnt, tgt);
    if (tid < 448) {
      int s = tid >> 6, dd = tid & 63;
      float t = 0;
#pragma unroll
      for (int j = 0; j < 16; ++j)
        t += aload(w + OFF_UPD + (size_t)((bb * 16 + j) * 7 + s) * 64 + dd);
      s_updl[s * 64 + dd] = t;
    }
    __syncthreads();

    // ---- GRU cell + FF (redundant per block)
    {
#pragma unroll 1
      for (int idx = tid; idx < 1344; idx += 1024) {
        int s = idx / 192, o = idx - s * 192;
        float g1 = gbih[o], g2 = gbhh[o];
#pragma unroll 4
        for (int j = 0; j < 64; ++j) {
          g1 += s_updl[s * 64 + j] * w[OFF_WIH + j * 192 + o];
          g2 += s_slots[s * 64 + j] * w[OFF_WHH + j * 192 + o];
        }
        s_scr1[s * 192 + o] = g1;
        s_scr2[s * 192 + o] = g2;
      }
      __syncthreads();
      if (tid < 448) {
        int s = tid >> 6, dd = tid & 63;
        float ir = s_scr1[s * 192 + dd],       hr = s_scr2[s * 192 + dd];
        float iz = s_scr1[s * 192 + 64 + dd],  hz = s_scr2[s * 192 + 64 + dd];
        float in_ = s_scr1[s * 192 + 128 + dd], hn = s_scr2[s * 192 + 128 + dd];
        float r = 1.f / (1.f + __expf(-(ir + hr)));
        float z = 1.f / (1.f + __expf(-(iz + hz)));
        float nn = tanhf(in_ + r * hn);
        s_updl[s * 64 + dd] = (1.f - z) * nn + z * s_slots[s * 64 + dd];
      }
      __syncthreads();
      if (wid < 7) {
        float h = s_updl[wid * 64 + lane];
        float m = wsum64(h) * (1.f / 64.f);
        float d0 = h - m;
        float va = wsum64(d0 * d0) * (1.f / 64.f);
        s_snl[wid * 64 + lane] = d0 * rsqrtf(va + 1e-5f) * lff_g[lane] + lff_b[lane];
      }
      __syncthreads();
      if (tid < 896) {
        int s = tid >> 7, i2 = tid & 127;
        float a1 = fc1b[i2];
#pragma unroll 4
        for (int j = 0; j < 64; ++j) a1 += s_snl[s * 64 + j] * w[OFF_F1T + j * 128 + i2];
        s_scr1[s * 128 + i2] = fmaxf(a1, 0.f);
      }
      __syncthreads();
      if (tid < 448) {
        int s = tid >> 6, dd = tid & 63;
        float a2 = fc2b[dd];
#pragma unroll 4
        for (int i2 = 0; i2 < 128; ++i2) a2 += s_scr1[s * 128 + i2] * w[OFF_F2T + i2 * 64 + dd];
        s_slots[s * 64 + dd] = s_updl[s * 64 + dd] + a2;
      }
      __syncthreads();
    }
    if (it < 2) slot_common(it + 1);
  }

  if (ib == 0 && tid < 448) out[(size_t)bb * 448 + tid] = s_slots[tid];
}

extern "C" void kernel_launch(void* const* d_in, const int* in_sizes, int n_in,
                              void* d_out, int out_size, void* d_ws, size_t ws_size,
                              hipStream_t stream) {
  (void)in_sizes; (void)n_in; (void)out_size; (void)ws_size;
  const float* inputs = (const float*)d_in[0];
  const float* sinit  = (const float*)d_in[1];
  const float* smu    = (const float*)d_in[2];
  const float* slsig  = (const float*)d_in[3];
  const float* Wq     = (const float*)d_in[4];
  const float* Wk     = (const float*)d_in[5];
  const float* Wv     = (const float*)d_in[6];
  const float* gWih   = (const float*)d_in[7];
  const float* gWhh   = (const float*)d_in[8];
  const float* gbih   = (const float*)d_in[9];
  const float* gbhh   = (const float*)d_in[10];
  const float* fc1W   = (const float*)d_in[11];
  const float* fc1b   = (const float*)d_in[12];
  const float* fc2W   = (const float*)d_in[13];
  const float* fc2b   = (const float*)d_in[14];
  const float* ling   = (const float*)d_in[15];
  const float* linb   = (const float*)d_in[16];
  const float* lslg   = (const float*)d_in[17];
  const float* lslb   = (const float*)d_in[18];
  const float* lffg   = (const float*)d_in[19];
  const float* lffb   = (const float*)d_in[20];
  const float* wiW    = (const float*)d_in[21];
  const float* wib    = (const float*)d_in[22];
  const float* wsW    = (const float*)d_in[23];
  const float* wsb    = (const float*)d_in[24];
  float* out = (float*)d_out;
  float* w   = (float*)d_ws;

  prep_kernel<<<dim3(64), dim3(256), 0, stream>>>(Wq, gWih, gWhh, fc1W, fc2W, w);
  slot_attn_kernel<<<dim3(256), dim3(1024), 0, stream>>>(
      inputs, sinit, smu, slsig, Wk, Wv, gbih, gbhh, fc1b, fc2b,
      ling, linb, lslg, lslb, lffg, lffb, wiW, wib, wsW, wsb, out, w);
}

// Round 2
// 2160.931 us; speedup vs baseline: 4.9127x; 4.9127x over previous
//
#include <hip/hip_runtime.h>
#include <math.h>

#define AGENTS __HIP_MEMORY_SCOPE_AGENT

constexpr int   CB   = 16;      // batches
constexpr int   CN   = 16384;   // inputs per batch
constexpr float LOG7 = 1.9459101090932196f;
constexpr float EPST = 1e-8f;

// ws layout (float offsets)
constexpr size_t OFF_PA  = 64;                       // [16][16][2]
constexpr size_t OFF_RED = 576;                      // [2][16][16][8]
constexpr size_t OFF_UPD = 4672;                     // [16][16][7][64]
constexpr size_t OFF_QSP = 119360;                   // [3][256][512]
constexpr size_t OFF_WQT = 512576;                   // [64][64]
constexpr size_t OFF_WIH = 516672;                   // [64][192]
constexpr size_t OFF_WHH = 528960;                   // [64][192]
constexpr size_t OFF_F1T = 541248;                   // [64][128]
constexpr size_t OFF_F2T = 549440;                   // [128][64]
constexpr size_t OFF_K   = 557632;                   // [16][16384][64]
constexpr size_t OFF_V   = OFF_K + (size_t)CB * CN * 64;

__device__ __forceinline__ float aload(const float* p) {
  return __hip_atomic_load(const_cast<float*>(p), __ATOMIC_RELAXED, AGENTS);
}
__device__ __forceinline__ void astore(float* p, float v) {
  __hip_atomic_store(p, v, __ATOMIC_RELAXED, AGENTS);
}
__device__ __forceinline__ float wsum64(float v) {
#pragma unroll
  for (int m = 1; m < 64; m <<= 1) v += __shfl_xor(v, m, 64);
  return v;
}
__device__ __forceinline__ float dot4(float4 a, float4 b) {
  return a.x * b.x + a.y * b.y + a.z * b.z + a.w * b.w;
}

// Lightweight inter-block barrier for the 16 blocks of one batch.
// All cross-block data moves via sc1 (agent-scope) atomics that bypass the
// non-coherent per-XCD L2, so NO __threadfence (buffer_wbl2/buffer_inv L2
// walks) is needed — only "my sc1 stores completed" = s_waitcnt vmcnt(0)
// per wave, before the relaxed counter increment.
__device__ __forceinline__ void batch_sync(unsigned* cnt, unsigned& tgt) {
  asm volatile("s_waitcnt vmcnt(0)" ::: "memory");
  __syncthreads();
  tgt += 16;
  if (threadIdx.x == 0) {
    __hip_atomic_fetch_add(cnt, 1u, __ATOMIC_RELAXED, AGENTS);
    unsigned v;
    do {
      v = __hip_atomic_load(cnt, __ATOMIC_RELAXED, AGENTS);
      if (v < tgt) __builtin_amdgcn_s_sleep(1);
    } while (v < tgt);
  }
  __syncthreads();
}

// reduce 7 per-thread values over all 16384 rows of the batch -> tot[0..6] (LDS)
__device__ __forceinline__ void reduce7_sync(float (&es)[7], float* __restrict__ wsp,
                                             float* s_redw, float* tot, int bb, int ib,
                                             unsigned* cnt, unsigned& tgt, int& rbuf) {
  const int tid = threadIdx.x, lane = tid & 63, wid = tid >> 6;
#pragma unroll
  for (int m = 1; m < 64; m <<= 1) {
#pragma unroll
    for (int s = 0; s < 7; ++s) es[s] += __shfl_xor(es[s], m, 64);
  }
  if (lane == 0) {
#pragma unroll
    for (int s = 0; s < 7; ++s) s_redw[wid * 8 + s] = es[s];
  }
  __syncthreads();
  float* rp = wsp + OFF_RED + (size_t)((rbuf * CB + bb) * 16) * 8;
  if (wid == 0) {
#pragma unroll
    for (int h = 0; h < 2; ++h) {
      int s = h * 4 + (lane >> 4);
      float v = 0.f;
      if (s < 7) v = s_redw[(lane & 15) * 8 + s];
      v += __shfl_xor(v, 1, 64); v += __shfl_xor(v, 2, 64);
      v += __shfl_xor(v, 4, 64); v += __shfl_xor(v, 8, 64);
      if ((lane & 15) == 0 && s < 7) astore(rp + ib * 8 + s, v);
    }
  }
  batch_sync(cnt, tgt);
  if (wid == 0) {
#pragma unroll
    for (int h = 0; h < 2; ++h) {
      int s = h * 4 + (lane >> 4);
      float v = 0.f;
      if (s < 7) v = aload(rp + (lane & 15) * 8 + s);
      v += __shfl_xor(v, 1, 64); v += __shfl_xor(v, 2, 64);
      v += __shfl_xor(v, 4, 64); v += __shfl_xor(v, 8, 64);
      if ((lane & 15) == 0 && s < 7) tot[s] = v;
    }
  }
  __syncthreads();
  rbuf ^= 1;
}

__global__ void prep_kernel(const float* __restrict__ Wq, const float* __restrict__ Wih,
                            const float* __restrict__ Whh, const float* __restrict__ f1,
                            const float* __restrict__ f2, float* __restrict__ w) {
  int idx = blockIdx.x * blockDim.x + threadIdx.x;
  int stride = gridDim.x * blockDim.x;
  if (idx < 16) reinterpret_cast<unsigned*>(w)[idx] = 0u;
  for (int i = idx; i < 64 * 64; i += stride) {
    int d = i / 64, j = i % 64;
    w[OFF_WQT + j * 64 + d] = Wq[d * 64 + j];
  }
  for (int i = idx; i < 192 * 64; i += stride) {
    int o = i / 64, j = i % 64;
    w[OFF_WIH + j * 192 + o] = Wih[o * 64 + j];
    w[OFF_WHH + j * 192 + o] = Whh[o * 64 + j];
  }
  for (int i = idx; i < 128 * 64; i += stride) {
    int o = i / 64, j = i % 64;
    w[OFF_F1T + j * 128 + o] = f1[o * 64 + j];
  }
  for (int i = idx; i < 64 * 128; i += stride) {
    int d = i / 128, j = i % 128;
    w[OFF_F2T + j * 64 + d] = f2[d * 128 + j];
  }
}

__launch_bounds__(1024, 4)
__global__ void slot_attn_kernel(
    const float* __restrict__ inputs, const float* __restrict__ sinit,
    const float* __restrict__ smu, const float* __restrict__ slsig,
    const float* __restrict__ Wk, const float* __restrict__ Wv,
    const float* __restrict__ gbih, const float* __restrict__ gbhh,
    const float* __restrict__ fc1b, const float* __restrict__ fc2b,
    const float* __restrict__ lin_g, const float* __restrict__ lin_b,
    const float* __restrict__ lsl_g, const float* __restrict__ lsl_b,
    const float* __restrict__ lff_g, const float* __restrict__ lff_b,
    const float* __restrict__ wi_W, const float* __restrict__ wi_b,
    const float* __restrict__ wsW, const float* __restrict__ wsB,
    float* __restrict__ out, float* __restrict__ w) {
  __shared__ float s_slots[448];
  __shared__ float s_snl[448];
  __shared__ float s_scr1[1344];
  __shared__ float s_scr2[1344];
  __shared__ float s_updl[448];
  __shared__ float s_T[8192];       // [1024][8]
  __shared__ float s_pupd[7168];    // [16][7][64]
  __shared__ float s_vh[48];        // v history [6][8]
  __shared__ float s_logb[8];
  __shared__ float s_gvl[8];
  __shared__ float s_tot[8];
  __shared__ float s_wl[8];
  __shared__ float s_redw[128];     // [16][8]
  __shared__ float s_misc[4];

  const int tid = threadIdx.x;
  const int lane = tid & 63, wid = tid >> 6;
  const int bb = blockIdx.x & 15;
  const int ib = blockIdx.x >> 4;
  const int nloc = ib * 1024 + tid;
  const size_t grow = (size_t)bb * CN + nloc;
  unsigned* cnt = reinterpret_cast<unsigned*>(w) + bb;
  unsigned tgt = 0;
  int rbuf = 0;
  float log_a;

  // ================= phase 0: LN + k/v/logit projections =================
  {
    const float* xin = inputs + grow * 64;
    float4 xa[16];
#pragma unroll
    for (int c = 0; c < 16; ++c) xa[c] = reinterpret_cast<const float4*>(xin)[c];
    float s1 = 0;
#pragma unroll
    for (int c = 0; c < 16; ++c) s1 += xa[c].x + xa[c].y + xa[c].z + xa[c].w;
    float mn = s1 * (1.f / 64.f);
    float s2 = 0;
#pragma unroll
    for (int c = 0; c < 16; ++c) {
      float dx = xa[c].x - mn, dy = xa[c].y - mn, dz = xa[c].z - mn, dw = xa[c].w - mn;
      s2 += dx * dx + dy * dy + dz * dz + dw * dw;
    }
    float rs = rsqrtf(s2 * (1.f / 64.f) + 1e-5f);
#pragma unroll
    for (int c = 0; c < 16; ++c) {
      float4 g4 = reinterpret_cast<const float4*>(lin_g)[c];
      float4 b4 = reinterpret_cast<const float4*>(lin_b)[c];
      xa[c].x = (xa[c].x - mn) * rs * g4.x + b4.x;
      xa[c].y = (xa[c].y - mn) * rs * g4.y + b4.y;
      xa[c].z = (xa[c].z - mn) * rs * g4.z + b4.z;
      xa[c].w = (xa[c].w - mn) * rs * g4.w + b4.w;
    }
    float lg = wi_b[0];
#pragma unroll
    for (int c = 0; c < 16; ++c) lg += dot4(xa[c], reinterpret_cast<const float4*>(wi_W)[c]);
    // k, v projections (W rows uniform -> scalar-cached loads)
#pragma unroll 1
    for (int half = 0; half < 2; ++half) {
      const float* W = half ? Wv : Wk;
      float* ob = w + (half ? OFF_V : OFF_K) + grow * 64;
#pragma unroll 1
      for (int oc = 0; oc < 8; ++oc) {
        float acc[8] = {0, 0, 0, 0, 0, 0, 0, 0};
#pragma unroll
        for (int c = 0; c < 16; ++c) {
          float4 xv = xa[c];
#pragma unroll
          for (int o8 = 0; o8 < 8; ++o8) {
            float4 w4 = reinterpret_cast<const float4*>(W + (size_t)(oc * 8 + o8) * 64)[c];
            acc[o8] += dot4(xv, w4);
          }
        }
        reinterpret_cast<float4*>(ob + oc * 8)[0] = make_float4(acc[0], acc[1], acc[2], acc[3]);
        reinterpret_cast<float4*>(ob + oc * 8)[1] = make_float4(acc[4], acc[5], acc[6], acc[7]);
      }
    }
    // batch softmax stats for 'a'
    float mx = lg;
#pragma unroll
    for (int m = 1; m < 64; m <<= 1) mx = fmaxf(mx, __shfl_xor(mx, m, 64));
    float se = wsum64(__expf(lg - mx));
    if (lane == 0) { s_redw[wid * 8 + 0] = mx; s_redw[wid * 8 + 1] = se; }
    __syncthreads();
    float* pa = w + OFF_PA + (size_t)bb * 32;
    if (wid == 0 && lane < 16) {
      float m0 = s_redw[lane * 8 + 0], e0 = s_redw[lane * 8 + 1];
#pragma unroll
      for (int mm = 1; mm < 16; mm <<= 1) {
        float m1 = __shfl_xor(m0, mm, 64), e1 = __shfl_xor(e0, mm, 64);
        float nm = fmaxf(m0, m1);
        e0 = e0 * __expf(m0 - nm) + e1 * __expf(m1 - nm);
        m0 = nm;
      }
      if (lane == 0) { astore(pa + ib * 2 + 0, m0); astore(pa + ib * 2 + 1, e0); }
    }
    batch_sync(cnt, tgt);
    if (wid == 0 && lane < 16) {
      float m0 = aload(pa + lane * 2 + 0), e0 = aload(pa + lane * 2 + 1);
#pragma unroll
      for (int mm = 1; mm < 16; mm <<= 1) {
        float m1 = __shfl_xor(m0, mm, 64), e1 = __shfl_xor(e0, mm, 64);
        float nm = fmaxf(m0, m1);
        e0 = e0 * __expf(m0 - nm) + e1 * __expf(m1 - nm);
        m0 = nm;
      }
      if (lane == 0) s_misc[0] = m0 + __logf(e0);
    }
    __syncthreads();
    log_a = lg - s_misc[0] + LOG7;
  }

  // slot phase common: LN(slots)->snl, q (+q2) spill, log_b
  auto slot_common = [&](int inst) {
    if (wid < 7) {
      float h = s_slots[wid * 64 + lane];
      float m = wsum64(h) * (1.f / 64.f);
      float d0 = h - m;
      float va = wsum64(d0 * d0) * (1.f / 64.f);
      float sn = d0 * rsqrtf(va + 1e-5f) * lsl_g[lane] + lsl_b[lane];
      s_snl[wid * 64 + lane] = sn;
      float pw = wsum64(sn * wsW[lane]);
      if (lane == 0) s_wl[wid] = pw + wsB[0];
    }
    __syncthreads();
    float* qsp = w + OFF_QSP + (size_t)(inst * 256 + blockIdx.x) * 512;
    if (tid < 448) {
      int s = tid >> 6, dd = tid & 63;
      float acc = 0;
#pragma unroll 4
      for (int j = 0; j < 64; ++j) acc += s_snl[s * 64 + j] * w[OFF_WQT + j * 64 + dd];
      qsp[s * 64 + dd] = acc;
      s_scr1[s * 64 + dd] = acc;
    }
    __syncthreads();
    if (wid < 7) {
      float qv = s_scr1[wid * 64 + lane];
      float q2 = wsum64(qv * qv);
      if (lane == 0) qsp[448 + wid] = q2;
    }
    if (tid == 0) {
      float mx = -1e30f;
#pragma unroll
      for (int s = 0; s < 7; ++s) mx = fmaxf(mx, s_wl[s]);
      float se = 0;
#pragma unroll
      for (int s = 0; s < 7; ++s) se += __expf(s_wl[s] - mx);
      float lse = mx + __logf(se);
#pragma unroll
      for (int s = 0; s < 7; ++s) s_logb[s] = s_wl[s] - lse + LOG7;
    }
    __syncthreads();
  };

  // init slots
  if (tid < 448) {
    int dd = tid & 63;
    s_slots[tid] = smu[dd] + __expf(slsig[dd]) * sinit[(size_t)bb * 448 + tid];
  }
  __syncthreads();
  slot_common(0);

  float p[7], u = 0.f;
  auto fwd5 = [&]() {
#pragma unroll 1
    for (int i = 1; i <= 5; ++i) {
      float t = 0;
#pragma unroll
      for (int s = 0; s < 7; ++s) t += __expf(p[s] + s_vh[(i - 1) * 8 + s]);
      u = log_a - __logf(t);
      float es[7];
#pragma unroll
      for (int s = 0; s < 7; ++s) es[s] = __expf(p[s] + u);
      reduce7_sync(es, w, s_redw, s_tot, bb, ib, cnt, tgt, rbuf);
      if (tid < 7) s_vh[i * 8 + tid] = s_logb[tid] - __logf(s_tot[tid]);
      __syncthreads();
    }
  };

#pragma unroll 1
  for (int it = 0; it < 3; ++it) {
    // ---- C = -cdist(k, q)
    {
      const float* kb = w + OFF_K + grow * 64;
      const float* qsp = w + OFF_QSP + (size_t)(it * 256 + blockIdx.x) * 512;
      float k2 = 0, kq[7] = {0, 0, 0, 0, 0, 0, 0};
#pragma unroll
      for (int c = 0; c < 16; ++c) {
        float4 kk = reinterpret_cast<const float4*>(kb)[c];
        k2 += dot4(kk, kk);
#pragma unroll
        for (int s = 0; s < 7; ++s)
          kq[s] += dot4(kk, reinterpret_cast<const float4*>(qsp + s * 64)[c]);
      }
#pragma unroll
      for (int s = 0; s < 7; ++s) {
        float sq = k2 + qsp[448 + s] - 2.f * kq[s];
        p[s] = -sqrtf(fmaxf(sq, 0.f) + 1e-12f);
      }
    }
    if (tid < 8) s_vh[tid] = 0.f;
    __syncthreads();

    // ---- MESH: 4 iterations of entropy-gradient descent on C
#pragma unroll 1
    for (int ms = 0; ms < 4; ++ms) {
      fwd5();
      float gp[7], guT = 0.f;
      {
        float es[7];
#pragma unroll
        for (int s = 0; s < 7; ++s) {
          float T = __expf(p[s] + u + s_vh[40 + s]);
          float gT = -(__logf(T + EPST) + T / (T + EPST));
          float g = gT * T;
          gp[s] = g; guT += g; es[s] = g;
        }
        reduce7_sync(es, w, s_redw, s_gvl, bb, ib, cnt, tgt, rbuf);  // gv_5
      }
#pragma unroll 1
      for (int i = 5; i >= 1; --i) {
        float t = 0;
#pragma unroll
        for (int s = 0; s < 7; ++s) t += __expf(p[s] + s_vh[(i - 1) * 8 + s]);
        float ui = log_a - __logf(t);
        float gu = (i == 5) ? guT : 0.f;
#pragma unroll
        for (int s = 0; s < 7; ++s) {
          float sn = __expf(p[s] + ui - s_logb[s] + s_vh[i * 8 + s]);
          float gz = -s_gvl[s] * sn;
          gp[s] += gz; gu += gz;
        }
        float gw[7];
#pragma unroll
        for (int s = 0; s < 7; ++s) {
          float sg = __expf(p[s] + s_vh[(i - 1) * 8 + s] - log_a + ui);
          gw[s] = -gu * sg;
          gp[s] += gw[s];
        }
        if (i > 1) reduce7_sync(gw, w, s_redw, s_gvl, bb, ib, cnt, tgt, rbuf);  // gv_{i-1}
      }
#pragma unroll
      for (int s = 0; s < 7; ++s) p[s] -= 5.0f * gp[s];
      if (tid < 8) s_vh[tid] = s_vh[40 + tid];  // warm-start v
      __syncthreads();
    }

    // ---- final sinkhorn (warm-started) -> attn row
    fwd5();
    float T7[7];
#pragma unroll
    for (int s = 0; s < 7; ++s) T7[s] = __expf(p[s] + u + s_vh[40 + s]);
    if (it == 2) {
      size_t ab = 7168 + (size_t)(bb * 7) * CN + nloc;
#pragma unroll
      for (int s = 0; s < 7; ++s) out[ab + (size_t)s * CN] = T7[s];
    }
#pragma unroll
    for (int s = 0; s < 7; ++s) s_T[tid * 8 + s] = T7[s];
    s_T[tid * 8 + 7] = 0.f;
    __syncthreads();

    // ---- updates = attn @ v  (per-wave column reduce, then batch combine)
    {
      const float* vb = w + OFF_V + (size_t)(bb * CN + ib * 1024 + wid * 64) * 64 + lane;
      float acc[7] = {0, 0, 0, 0, 0, 0, 0};
#pragma unroll 4
      for (int n = 0; n < 64; ++n) {
        float vv = vb[(size_t)n * 64];
        const float* tr = &s_T[(wid * 64 + n) * 8];
        acc[0] += tr[0] * vv; acc[1] += tr[1] * vv; acc[2] += tr[2] * vv;
        acc[3] += tr[3] * vv; acc[4] += tr[4] * vv; acc[5] += tr[5] * vv;
        acc[6] += tr[6] * vv;
      }
#pragma unroll
      for (int s = 0; s < 7; ++s) s_pupd[(wid * 7 + s) * 64 + lane] = acc[s];
    }
    __syncthreads();
    if (tid < 448) {
      int s = tid >> 6, dd = tid & 63;
      float t = 0;
#pragma unroll
      for (int w16 = 0; w16 < 16; ++w16) t += s_pupd[(w16 * 7 + s) * 64 + dd];
      astore(w + OFF_UPD + (size_t)((bb * 16 + ib) * 7 + s) * 64 + dd, t);
    }
    batch_sync(cnt, tgt);
    if (tid < 448) {
      int s = tid >> 6, dd = tid & 63;
      float t = 0;
#pragma unroll
      for (int j = 0; j < 16; ++j)
        t += aload(w + OFF_UPD + (size_t)((bb * 16 + j) * 7 + s) * 64 + dd);
      s_updl[s * 64 + dd] = t;
    }
    __syncthreads();

    // ---- GRU cell + FF (redundant per block)
    {
#pragma unroll 1
      for (int idx = tid; idx < 1344; idx += 1024) {
        int s = idx / 192, o = idx - s * 192;
        float g1 = gbih[o], g2 = gbhh[o];
#pragma unroll 4
        for (int j = 0; j < 64; ++j) {
          g1 += s_updl[s * 64 + j] * w[OFF_WIH + j * 192 + o];
          g2 += s_slots[s * 64 + j] * w[OFF_WHH + j * 192 + o];
        }
        s_scr1[s * 192 + o] = g1;
        s_scr2[s * 192 + o] = g2;
      }
      __syncthreads();
      if (tid < 448) {
        int s = tid >> 6, dd = tid & 63;
        float ir = s_scr1[s * 192 + dd],       hr = s_scr2[s * 192 + dd];
        float iz = s_scr1[s * 192 + 64 + dd],  hz = s_scr2[s * 192 + 64 + dd];
        float in_ = s_scr1[s * 192 + 128 + dd], hn = s_scr2[s * 192 + 128 + dd];
        float r = 1.f / (1.f + __expf(-(ir + hr)));
        float z = 1.f / (1.f + __expf(-(iz + hz)));
        float nn = tanhf(in_ + r * hn);
        s_updl[s * 64 + dd] = (1.f - z) * nn + z * s_slots[s * 64 + dd];
      }
      __syncthreads();
      if (wid < 7) {
        float h = s_updl[wid * 64 + lane];
        float m = wsum64(h) * (1.f / 64.f);
        float d0 = h - m;
        float va = wsum64(d0 * d0) * (1.f / 64.f);
        s_snl[wid * 64 + lane] = d0 * rsqrtf(va + 1e-5f) * lff_g[lane] + lff_b[lane];
      }
      __syncthreads();
      if (tid < 896) {
        int s = tid >> 7, i2 = tid & 127;
        float a1 = fc1b[i2];
#pragma unroll 4
        for (int j = 0; j < 64; ++j) a1 += s_snl[s * 64 + j] * w[OFF_F1T + j * 128 + i2];
        s_scr1[s * 128 + i2] = fmaxf(a1, 0.f);
      }
      __syncthreads();
      if (tid < 448) {
        int s = tid >> 6, dd = tid & 63;
        float a2 = fc2b[dd];
#pragma unroll 4
        for (int i2 = 0; i2 < 128; ++i2) a2 += s_scr1[s * 128 + i2] * w[OFF_F2T + i2 * 64 + dd];
        s_slots[s * 64 + dd] = s_updl[s * 64 + dd] + a2;
      }
      __syncthreads();
    }
    if (it < 2) slot_common(it + 1);
  }

  if (ib == 0 && tid < 448) out[(size_t)bb * 448 + tid] = s_slots[tid];
}

extern "C" void kernel_launch(void* const* d_in, const int* in_sizes, int n_in,
                              void* d_out, int out_size, void* d_ws, size_t ws_size,
                              hipStream_t stream) {
  (void)in_sizes; (void)n_in; (void)out_size; (void)ws_size;
  const float* inputs = (const float*)d_in[0];
  const float* sinit  = (const float*)d_in[1];
  const float* smu    = (const float*)d_in[2];
  const float* slsig  = (const float*)d_in[3];
  const float* Wq     = (const float*)d_in[4];
  const float* Wk     = (const float*)d_in[5];
  const float* Wv     = (const float*)d_in[6];
  const float* gWih   = (const float*)d_in[7];
  const float* gWhh   = (const float*)d_in[8];
  const float* gbih   = (const float*)d_in[9];
  const float* gbhh   = (const float*)d_in[10];
  const float* fc1W   = (const float*)d_in[11];
  const float* fc1b   = (const float*)d_in[12];
  const float* fc2W   = (const float*)d_in[13];
  const float* fc2b   = (const float*)d_in[14];
  const float* ling   = (const float*)d_in[15];
  const float* linb   = (const float*)d_in[16];
  const float* lslg   = (const float*)d_in[17];
  const float* lslb   = (const float*)d_in[18];
  const float* lffg   = (const float*)d_in[19];
  const float* lffb   = (const float*)d_in[20];
  const float* wiW    = (const float*)d_in[21];
  const float* wib    = (const float*)d_in[22];
  const float* wsW    = (const float*)d_in[23];
  const float* wsb    = (const float*)d_in[24];
  float* out = (float*)d_out;
  float* w   = (float*)d_ws;

  prep_kernel<<<dim3(64), dim3(256), 0, stream>>>(Wq, gWih, gWhh, fc1W, fc2W, w);
  slot_attn_kernel<<<dim3(256), dim3(1024), 0, stream>>>(
      inputs, sinit, smu, slsig, Wk, Wv, gbih, gbhh, fc1b, fc2b,
      ling, linb, lslg, lslb, lffg, lffb, wiW, wib, wsW, wsb, out, w);
}

// Round 3
// 2006.797 us; speedup vs baseline: 5.2900x; 1.0768x over previous
//
#include <hip/hip_runtime.h>
#include <math.h>

#define AGENTS __HIP_MEMORY_SCOPE_AGENT

constexpr int   CB   = 16;      // batches
constexpr int   CN   = 16384;   // inputs per batch
constexpr float LOG7 = 1.9459101090932196f;
constexpr float EPST = 1e-8f;

// ws layout (float offsets)
// counters: [16][64] uints (256B-spaced lines, one per batch) = floats [0,1024)
constexpr size_t OFF_PA  = 1088;                     // [16][16][2]
constexpr size_t OFF_RED = 1600;                     // [2][16][16][8]
constexpr size_t OFF_UPD = 5696;                     // [16][16][7][64]
constexpr size_t OFF_QSP = 120384;                   // [3][256][512]
constexpr size_t OFF_WQT = 513600;                   // [64][64]
constexpr size_t OFF_WIH = 517696;                   // [64][192]
constexpr size_t OFF_WHH = 529984;                   // [64][192]
constexpr size_t OFF_F1T = 542272;                   // [64][128]
constexpr size_t OFF_F2T = 550464;                   // [128][64]
constexpr size_t OFF_K   = 558656;                   // [16][16384][64]
constexpr size_t OFF_V   = OFF_K + (size_t)CB * CN * 64;

__device__ __forceinline__ float aload(const float* p) {
  return __hip_atomic_load(const_cast<float*>(p), __ATOMIC_RELAXED, AGENTS);
}
__device__ __forceinline__ void astore(float* p, float v) {
  __hip_atomic_store(p, v, __ATOMIC_RELAXED, AGENTS);
}
__device__ __forceinline__ float wsum64(float v) {
#pragma unroll
  for (int m = 1; m < 64; m <<= 1) v += __shfl_xor(v, m, 64);
  return v;
}
__device__ __forceinline__ float dot4(float4 a, float4 b) {
  return a.x * b.x + a.y * b.y + a.z * b.z + a.w * b.w;
}

// Lightweight inter-block barrier for the 16 blocks of one batch.
// All cross-block data moves via sc1 (agent-scope) atomics that bypass the
// non-coherent per-XCD L2, so NO __threadfence is needed — only "my sc1
// stores completed" = s_waitcnt vmcnt(0) per wave, before the relaxed
// counter increment. Each batch's counter sits in its own 256B-spaced line.
__device__ __forceinline__ void batch_sync(unsigned* cnt, unsigned& tgt) {
  asm volatile("s_waitcnt vmcnt(0)" ::: "memory");
  __syncthreads();
  tgt += 16;
  if (threadIdx.x == 0) {
    __hip_atomic_fetch_add(cnt, 1u, __ATOMIC_RELAXED, AGENTS);
    unsigned v;
    do {
      v = __hip_atomic_load(cnt, __ATOMIC_RELAXED, AGENTS);
      if (v < tgt) __builtin_amdgcn_s_sleep(1);
    } while (v < tgt);
  }
  __syncthreads();
}

// reduce 7 per-thread values over all 16384 rows of the batch -> tot[0..6] (LDS)
__device__ __forceinline__ void reduce7_sync(float (&es)[7], float* __restrict__ wsp,
                                             float* s_redw, float* tot, int bb, int ib,
                                             unsigned* cnt, unsigned& tgt, int& rbuf) {
  const int tid = threadIdx.x, lane = tid & 63, wid = tid >> 6;
#pragma unroll
  for (int m = 1; m < 64; m <<= 1) {
#pragma unroll
    for (int s = 0; s < 7; ++s) es[s] += __shfl_xor(es[s], m, 64);
  }
  if (lane == 0) {
#pragma unroll
    for (int s = 0; s < 7; ++s) s_redw[wid * 8 + s] = es[s];
  }
  __syncthreads();
  float* rp = wsp + OFF_RED + (size_t)((rbuf * CB + bb) * 16) * 8;
  if (wid == 0) {
#pragma unroll
    for (int h = 0; h < 2; ++h) {
      int s = h * 4 + (lane >> 4);
      float v = 0.f;
      if (s < 7) v = s_redw[(lane & 15) * 8 + s];
      v += __shfl_xor(v, 1, 64); v += __shfl_xor(v, 2, 64);
      v += __shfl_xor(v, 4, 64); v += __shfl_xor(v, 8, 64);
      if ((lane & 15) == 0 && s < 7) astore(rp + ib * 8 + s, v);
    }
  }
  batch_sync(cnt, tgt);
  if (wid == 0) {
#pragma unroll
    for (int h = 0; h < 2; ++h) {
      int s = h * 4 + (lane >> 4);
      float v = 0.f;
      if (s < 7) v = aload(rp + (lane & 15) * 8 + s);
      v += __shfl_xor(v, 1, 64); v += __shfl_xor(v, 2, 64);
      v += __shfl_xor(v, 4, 64); v += __shfl_xor(v, 8, 64);
      if ((lane & 15) == 0 && s < 7) tot[s] = v;
    }
  }
  __syncthreads();
  rbuf ^= 1;
}

__global__ void prep_kernel(const float* __restrict__ Wq, const float* __restrict__ Wih,
                            const float* __restrict__ Whh, const float* __restrict__ f1,
                            const float* __restrict__ f2, float* __restrict__ w) {
  int idx = blockIdx.x * blockDim.x + threadIdx.x;
  int stride = gridDim.x * blockDim.x;
  if (idx < 1024) reinterpret_cast<unsigned*>(w)[idx] = 0u;
  for (int i = idx; i < 64 * 64; i += stride) {
    int d = i / 64, j = i % 64;
    w[OFF_WQT + j * 64 + d] = Wq[d * 64 + j];
  }
  for (int i = idx; i < 192 * 64; i += stride) {
    int o = i / 64, j = i % 64;
    w[OFF_WIH + j * 192 + o] = Wih[o * 64 + j];
    w[OFF_WHH + j * 192 + o] = Whh[o * 64 + j];
  }
  for (int i = idx; i < 128 * 64; i += stride) {
    int o = i / 64, j = i % 64;
    w[OFF_F1T + j * 128 + o] = f1[o * 64 + j];
  }
  for (int i = idx; i < 64 * 128; i += stride) {
    int d = i / 128, j = i % 128;
    w[OFF_F2T + j * 64 + d] = f2[d * 128 + j];
  }
}

__launch_bounds__(1024, 4)
__global__ void slot_attn_kernel(
    const float* __restrict__ inputs, const float* __restrict__ sinit,
    const float* __restrict__ smu, const float* __restrict__ slsig,
    const float* __restrict__ Wk, const float* __restrict__ Wv,
    const float* __restrict__ gbih, const float* __restrict__ gbhh,
    const float* __restrict__ fc1b, const float* __restrict__ fc2b,
    const float* __restrict__ lin_g, const float* __restrict__ lin_b,
    const float* __restrict__ lsl_g, const float* __restrict__ lsl_b,
    const float* __restrict__ lff_g, const float* __restrict__ lff_b,
    const float* __restrict__ wi_W, const float* __restrict__ wi_b,
    const float* __restrict__ wsW, const float* __restrict__ wsB,
    float* __restrict__ out, float* __restrict__ w) {
  __shared__ float s_slots[448];
  __shared__ float s_snl[448];
  __shared__ float s_scr1[1344];
  __shared__ float s_scr2[1344];
  __shared__ float s_updl[448];
  __shared__ float s_T[8192];       // [1024][8]
  __shared__ float s_pupd[7168];    // [16][7][64]
  __shared__ float s_vh[48];        // v history [6][8]
  __shared__ float s_logb[8];
  __shared__ float s_gvl[8];
  __shared__ float s_tot[8];
  __shared__ float s_wl[8];
  __shared__ float s_redw[128];     // [16][8]
  __shared__ float s_misc[4];

  const int tid = threadIdx.x;
  const int lane = tid & 63, wid = tid >> 6;
  const int bb = blockIdx.x & 15;
  const int ib = blockIdx.x >> 4;
  const int nloc = ib * 1024 + tid;
  const size_t grow = (size_t)bb * CN + nloc;
  unsigned* cnt = reinterpret_cast<unsigned*>(w) + (size_t)bb * 64;
  unsigned tgt = 0;
  int rbuf = 0;
  float log_a;

  // ================= phase 0: LN + k/v/logit projections =================
  {
    const float* xin = inputs + grow * 64;
    float4 xa[16];
#pragma unroll
    for (int c = 0; c < 16; ++c) xa[c] = reinterpret_cast<const float4*>(xin)[c];
    float s1 = 0;
#pragma unroll
    for (int c = 0; c < 16; ++c) s1 += xa[c].x + xa[c].y + xa[c].z + xa[c].w;
    float mn = s1 * (1.f / 64.f);
    float s2 = 0;
#pragma unroll
    for (int c = 0; c < 16; ++c) {
      float dx = xa[c].x - mn, dy = xa[c].y - mn, dz = xa[c].z - mn, dw = xa[c].w - mn;
      s2 += dx * dx + dy * dy + dz * dz + dw * dw;
    }
    float rs = rsqrtf(s2 * (1.f / 64.f) + 1e-5f);
#pragma unroll
    for (int c = 0; c < 16; ++c) {
      float4 g4 = reinterpret_cast<const float4*>(lin_g)[c];
      float4 b4 = reinterpret_cast<const float4*>(lin_b)[c];
      xa[c].x = (xa[c].x - mn) * rs * g4.x + b4.x;
      xa[c].y = (xa[c].y - mn) * rs * g4.y + b4.y;
      xa[c].z = (xa[c].z - mn) * rs * g4.z + b4.z;
      xa[c].w = (xa[c].w - mn) * rs * g4.w + b4.w;
    }
    float lg = wi_b[0];
#pragma unroll
    for (int c = 0; c < 16; ++c) lg += dot4(xa[c], reinterpret_cast<const float4*>(wi_W)[c]);
    // k, v projections (W rows uniform -> scalar-cached loads)
#pragma unroll 1
    for (int half = 0; half < 2; ++half) {
      const float* W = half ? Wv : Wk;
      float* ob = w + (half ? OFF_V : OFF_K) + grow * 64;
#pragma unroll 1
      for (int oc = 0; oc < 8; ++oc) {
        float acc[8] = {0, 0, 0, 0, 0, 0, 0, 0};
#pragma unroll
        for (int c = 0; c < 16; ++c) {
          float4 xv = xa[c];
#pragma unroll
          for (int o8 = 0; o8 < 8; ++o8) {
            float4 w4 = reinterpret_cast<const float4*>(W + (size_t)(oc * 8 + o8) * 64)[c];
            acc[o8] += dot4(xv, w4);
          }
        }
        reinterpret_cast<float4*>(ob + oc * 8)[0] = make_float4(acc[0], acc[1], acc[2], acc[3]);
        reinterpret_cast<float4*>(ob + oc * 8)[1] = make_float4(acc[4], acc[5], acc[6], acc[7]);
      }
    }
    // batch softmax stats for 'a'
    float mx = lg;
#pragma unroll
    for (int m = 1; m < 64; m <<= 1) mx = fmaxf(mx, __shfl_xor(mx, m, 64));
    float se = wsum64(__expf(lg - mx));
    if (lane == 0) { s_redw[wid * 8 + 0] = mx; s_redw[wid * 8 + 1] = se; }
    __syncthreads();
    float* pa = w + OFF_PA + (size_t)bb * 32;
    if (wid == 0 && lane < 16) {
      float m0 = s_redw[lane * 8 + 0], e0 = s_redw[lane * 8 + 1];
#pragma unroll
      for (int mm = 1; mm < 16; mm <<= 1) {
        float m1 = __shfl_xor(m0, mm, 64), e1 = __shfl_xor(e0, mm, 64);
        float nm = fmaxf(m0, m1);
        e0 = e0 * __expf(m0 - nm) + e1 * __expf(m1 - nm);
        m0 = nm;
      }
      if (lane == 0) { astore(pa + ib * 2 + 0, m0); astore(pa + ib * 2 + 1, e0); }
    }
    batch_sync(cnt, tgt);
    if (wid == 0 && lane < 16) {
      float m0 = aload(pa + lane * 2 + 0), e0 = aload(pa + lane * 2 + 1);
#pragma unroll
      for (int mm = 1; mm < 16; mm <<= 1) {
        float m1 = __shfl_xor(m0, mm, 64), e1 = __shfl_xor(e0, mm, 64);
        float nm = fmaxf(m0, m1);
        e0 = e0 * __expf(m0 - nm) + e1 * __expf(m1 - nm);
        m0 = nm;
      }
      if (lane == 0) s_misc[0] = m0 + __logf(e0);
    }
    __syncthreads();
    log_a = lg - s_misc[0] + LOG7;
  }

  // slot phase common: LN(slots)->snl, q (+q2) spill, log_b
  auto slot_common = [&](int inst) {
    if (wid < 7) {
      float h = s_slots[wid * 64 + lane];
      float m = wsum64(h) * (1.f / 64.f);
      float d0 = h - m;
      float va = wsum64(d0 * d0) * (1.f / 64.f);
      float sn = d0 * rsqrtf(va + 1e-5f) * lsl_g[lane] + lsl_b[lane];
      s_snl[wid * 64 + lane] = sn;
      float pw = wsum64(sn * wsW[lane]);
      if (lane == 0) s_wl[wid] = pw + wsB[0];
    }
    __syncthreads();
    float* qsp = w + OFF_QSP + (size_t)(inst * 256 + blockIdx.x) * 512;
    if (tid < 448) {
      int s = tid >> 6, dd = tid & 63;
      float acc = 0;
#pragma unroll 4
      for (int j = 0; j < 64; ++j) acc += s_snl[s * 64 + j] * w[OFF_WQT + j * 64 + dd];
      qsp[s * 64 + dd] = acc;
      s_scr1[s * 64 + dd] = acc;
    }
    __syncthreads();
    if (wid < 7) {
      float qv = s_scr1[wid * 64 + lane];
      float q2 = wsum64(qv * qv);
      if (lane == 0) qsp[448 + wid] = q2;
    }
    if (tid == 0) {
      float mx = -1e30f;
#pragma unroll
      for (int s = 0; s < 7; ++s) mx = fmaxf(mx, s_wl[s]);
      float se = 0;
#pragma unroll
      for (int s = 0; s < 7; ++s) se += __expf(s_wl[s] - mx);
      float lse = mx + __logf(se);
#pragma unroll
      for (int s = 0; s < 7; ++s) s_logb[s] = s_wl[s] - lse + LOG7;
    }
    __syncthreads();
  };

  // init slots
  if (tid < 448) {
    int dd = tid & 63;
    s_slots[tid] = smu[dd] + __expf(slsig[dd]) * sinit[(size_t)bb * 448 + tid];
  }
  __syncthreads();
  slot_common(0);

  float p[7], u = 0.f;
  auto fwd5 = [&]() {
#pragma unroll 1
    for (int i = 1; i <= 5; ++i) {
      float t = 0;
#pragma unroll
      for (int s = 0; s < 7; ++s) t += __expf(p[s] + s_vh[(i - 1) * 8 + s]);
      u = log_a - __logf(t);
      float es[7];
#pragma unroll
      for (int s = 0; s < 7; ++s) es[s] = __expf(p[s] + u);
      reduce7_sync(es, w, s_redw, s_tot, bb, ib, cnt, tgt, rbuf);
      if (tid < 7) s_vh[i * 8 + tid] = s_logb[tid] - __logf(s_tot[tid]);
      __syncthreads();
    }
  };

#pragma unroll 1
  for (int it = 0; it < 3; ++it) {
    // ---- C = -cdist(k, q)
    {
      const float* kb = w + OFF_K + grow * 64;
      const float* qsp = w + OFF_QSP + (size_t)(it * 256 + blockIdx.x) * 512;
      float k2 = 0, kq[7] = {0, 0, 0, 0, 0, 0, 0};
#pragma unroll
      for (int c = 0; c < 16; ++c) {
        float4 kk = reinterpret_cast<const float4*>(kb)[c];
        k2 += dot4(kk, kk);
#pragma unroll
        for (int s = 0; s < 7; ++s)
          kq[s] += dot4(kk, reinterpret_cast<const float4*>(qsp + s * 64)[c]);
      }
#pragma unroll
      for (int s = 0; s < 7; ++s) {
        float sq = k2 + qsp[448 + s] - 2.f * kq[s];
        p[s] = -sqrtf(fmaxf(sq, 0.f) + 1e-12f);
      }
    }
    if (tid < 8) s_vh[tid] = 0.f;
    __syncthreads();

    // ---- MESH: 4 iterations of entropy-gradient descent on C
#pragma unroll 1
    for (int ms = 0; ms < 4; ++ms) {
      fwd5();
      float gp[7], guT = 0.f;
      {
        float es[7];
#pragma unroll
        for (int s = 0; s < 7; ++s) {
          float T = __expf(p[s] + u + s_vh[40 + s]);
          float gT = -(__logf(T + EPST) + T / (T + EPST));
          float g = gT * T;
          gp[s] = g; guT += g; es[s] = g;
        }
        reduce7_sync(es, w, s_redw, s_gvl, bb, ib, cnt, tgt, rbuf);  // gv_5
      }
#pragma unroll 1
      for (int i = 5; i >= 1; --i) {
        float t = 0;
#pragma unroll
        for (int s = 0; s < 7; ++s) t += __expf(p[s] + s_vh[(i - 1) * 8 + s]);
        float ui = log_a - __logf(t);
        float gu = (i == 5) ? guT : 0.f;
#pragma unroll
        for (int s = 0; s < 7; ++s) {
          float sn = __expf(p[s] + ui - s_logb[s] + s_vh[i * 8 + s]);
          float gz = -s_gvl[s] * sn;
          gp[s] += gz; gu += gz;
        }
        float gw[7];
#pragma unroll
        for (int s = 0; s < 7; ++s) {
          float sg = __expf(p[s] + s_vh[(i - 1) * 8 + s] - log_a + ui);
          gw[s] = -gu * sg;
          gp[s] += gw[s];
        }
        if (i > 1) reduce7_sync(gw, w, s_redw, s_gvl, bb, ib, cnt, tgt, rbuf);  // gv_{i-1}
      }
#pragma unroll
      for (int s = 0; s < 7; ++s) p[s] -= 5.0f * gp[s];
      if (tid < 8) s_vh[tid] = s_vh[40 + tid];  // warm-start v
      __syncthreads();
    }

    // ---- final sinkhorn (warm-started) -> attn row
    fwd5();
    float T7[7];
#pragma unroll
    for (int s = 0; s < 7; ++s) T7[s] = __expf(p[s] + u + s_vh[40 + s]);
    if (it == 2) {
      size_t ab = 7168 + (size_t)(bb * 7) * CN + nloc;
#pragma unroll
      for (int s = 0; s < 7; ++s) out[ab + (size_t)s * CN] = T7[s];
    }
#pragma unroll
    for (int s = 0; s < 7; ++s) s_T[tid * 8 + s] = T7[s];
    s_T[tid * 8 + 7] = 0.f;
    __syncthreads();

    // ---- updates = attn @ v  (per-wave column reduce, then batch combine)
    {
      const float* vb = w + OFF_V + (size_t)(bb * CN + ib * 1024 + wid * 64) * 64 + lane;
      float acc[7] = {0, 0, 0, 0, 0, 0, 0};
#pragma unroll 4
      for (int n = 0; n < 64; ++n) {
        float vv = vb[(size_t)n * 64];
        const float* tr = &s_T[(wid * 64 + n) * 8];
        acc[0] += tr[0] * vv; acc[1] += tr[1] * vv; acc[2] += tr[2] * vv;
        acc[3] += tr[3] * vv; acc[4] += tr[4] * vv; acc[5] += tr[5] * vv;
        acc[6] += tr[6] * vv;
      }
#pragma unroll
      for (int s = 0; s < 7; ++s) s_pupd[(wid * 7 + s) * 64 + lane] = acc[s];
    }
    __syncthreads();
    if (tid < 448) {
      int s = tid >> 6, dd = tid & 63;
      float t = 0;
#pragma unroll
      for (int w16 = 0; w16 < 16; ++w16) t += s_pupd[(w16 * 7 + s) * 64 + dd];
      astore(w + OFF_UPD + (size_t)((bb * 16 + ib) * 7 + s) * 64 + dd, t);
    }
    batch_sync(cnt, tgt);
    if (tid < 448) {
      int s = tid >> 6, dd = tid & 63;
      float t = 0;
#pragma unroll
      for (int j = 0; j < 16; ++j)
        t += aload(w + OFF_UPD + (size_t)((bb * 16 + j) * 7 + s) * 64 + dd);
      s_updl[s * 64 + dd] = t;
    }
    __syncthreads();

    // ---- GRU cell + FF (redundant per block)
    {
#pragma unroll 1
      for (int idx = tid; idx < 1344; idx += 1024) {
        int s = idx / 192, o = idx - s * 192;
        float g1 = gbih[o], g2 = gbhh[o];
#pragma unroll 4
        for (int j = 0; j < 64; ++j) {
          g1 += s_updl[s * 64 + j] * w[OFF_WIH + j * 192 + o];
          g2 += s_slots[s * 64 + j] * w[OFF_WHH + j * 192 + o];
        }
        s_scr1[s * 192 + o] = g1;
        s_scr2[s * 192 + o] = g2;
      }
      __syncthreads();
      if (tid < 448) {
        int s = tid >> 6, dd = tid & 63;
        float ir = s_scr1[s * 192 + dd],       hr = s_scr2[s * 192 + dd];
        float iz = s_scr1[s * 192 + 64 + dd],  hz = s_scr2[s * 192 + 64 + dd];
        float in_ = s_scr1[s * 192 + 128 + dd], hn = s_scr2[s * 192 + 128 + dd];
        float r = 1.f / (1.f + __expf(-(ir + hr)));
        float z = 1.f / (1.f + __expf(-(iz + hz)));
        float nn = tanhf(in_ + r * hn);
        s_updl[s * 64 + dd] = (1.f - z) * nn + z * s_slots[s * 64 + dd];
      }
      __syncthreads();
      if (wid < 7) {
        float h = s_updl[wid * 64 + lane];
        float m = wsum64(h) * (1.f / 64.f);
        float d0 = h - m;
        float va = wsum64(d0 * d0) * (1.f / 64.f);
        s_snl[wid * 64 + lane] = d0 * rsqrtf(va + 1e-5f) * lff_g[lane] + lff_b[lane];
      }
      __syncthreads();
      if (tid < 896) {
        int s = tid >> 7, i2 = tid & 127;
        float a1 = fc1b[i2];
#pragma unroll 4
        for (int j = 0; j < 64; ++j) a1 += s_snl[s * 64 + j] * w[OFF_F1T + j * 128 + i2];
        s_scr1[s * 128 + i2] = fmaxf(a1, 0.f);
      }
      __syncthreads();
      if (tid < 448) {
        int s = tid >> 6, dd = tid & 63;
        float a2 = fc2b[dd];
#pragma unroll 4
        for (int i2 = 0; i2 < 128; ++i2) a2 += s_scr1[s * 128 + i2] * w[OFF_F2T + i2 * 64 + dd];
        s_slots[s * 64 + dd] = s_updl[s * 64 + dd] + a2;
      }
      __syncthreads();
    }
    if (it < 2) slot_common(it + 1);
  }

  if (ib == 0 && tid < 448) out[(size_t)bb * 448 + tid] = s_slots[tid];
}

extern "C" void kernel_launch(void* const* d_in, const int* in_sizes, int n_in,
                              void* d_out, int out_size, void* d_ws, size_t ws_size,
                              hipStream_t stream) {
  (void)in_sizes; (void)n_in; (void)out_size; (void)ws_size;
  const float* inputs = (const float*)d_in[0];
  const float* sinit  = (const float*)d_in[1];
  const float* smu    = (const float*)d_in[2];
  const float* slsig  = (const float*)d_in[3];
  const float* Wq     = (const float*)d_in[4];
  const float* Wk     = (const float*)d_in[5];
  const float* Wv     = (const float*)d_in[6];
  const float* gWih   = (const float*)d_in[7];
  const float* gWhh   = (const float*)d_in[8];
  const float* gbih   = (const float*)d_in[9];
  const float* gbhh   = (const float*)d_in[10];
  const float* fc1W   = (const float*)d_in[11];
  const float* fc1b   = (const float*)d_in[12];
  const float* fc2W   = (const float*)d_in[13];
  const float* fc2b   = (const float*)d_in[14];
  const float* ling   = (const float*)d_in[15];
  const float* linb   = (const float*)d_in[16];
  const float* lslg   = (const float*)d_in[17];
  const float* lslb   = (const float*)d_in[18];
  const float* lffg   = (const float*)d_in[19];
  const float* lffb   = (const float*)d_in[20];
  const float* wiW    = (const float*)d_in[21];
  const float* wib    = (const float*)d_in[22];
  const float* wsW    = (const float*)d_in[23];
  const float* wsb    = (const float*)d_in[24];
  float* out = (float*)d_out;
  float* w   = (float*)d_ws;

  prep_kernel<<<dim3(64), dim3(256), 0, stream>>>(Wq, gWih, gWhh, fc1W, fc2W, w);
  slot_attn_kernel<<<dim3(256), dim3(1024), 0, stream>>>(
      inputs, sinit, smu, slsig, Wk, Wv, gbih, gbhh, fc1b, fc2b,
      ling, linb, lslg, lslb, lffg, lffb, wiW, wib, wsW, wsb, out, w);
}